// Round 3
// baseline (3732.494 us; speedup 1.0000x reference)
//
#include <hip/hip_runtime.h>
#include <hip/hip_bf16.h>
#include <math.h>

#define DM 768
#define NH 12
#define DH 64
#define DMLP 3072
#define BATCH 8
#define SEQ 1024
#define NTOK (BATCH*SEQ)
#define QKVN (3*DM)
#define LN_EPS 1e-5f

typedef __hip_bfloat16 bf16;

__device__ __forceinline__ float b2f(bf16 x){ return __bfloat162float(x); }
__device__ __forceinline__ float us2f(unsigned short u){
    unsigned int i = ((unsigned int)u) << 16; float f; __builtin_memcpy(&f, &i, 4); return f;
}
__device__ __forceinline__ bf16 f2b(float f){ return __float2bfloat16(f); }
__device__ __forceinline__ float tof(float x){ return x; }
__device__ __forceinline__ float tof(bf16 x){ return __bfloat162float(x); }

__device__ __forceinline__ float gelu_f(float x){
    float x3 = x*x*x;
    return 0.5f*x*(1.0f + tanhf(0.7978845608028654f*(x + 0.044715f*x3)));
}

// ---------------- prep: repack W_Q/W_K/W_V (fp32 [12,768,64]) -> fp32 [768, 2304] K x N ----------------
__global__ __launch_bounds__(256) void prep_wqkv(const float* __restrict__ Wq,
                                                 const float* __restrict__ Wk,
                                                 const float* __restrict__ Wv,
                                                 float* __restrict__ out)
{
    int idx = blockIdx.x*256 + threadIdx.x;
    if (idx >= DM*QKVN) return;
    int k = idx / QKVN;
    int c = idx % QKVN;
    int which = c / DM;
    int hc = c % DM;
    int h = hc / DH, e = hc % DH;
    const float* W = (which == 0) ? Wq : ((which == 1) ? Wk : Wv);
    out[idx] = W[(h*DM + k)*DH + e];   // W_*[h, k, e]
}

// concat b_Q|b_K|b_V (each [12,64] fp32, flat 768) -> [2304] fp32
__global__ __launch_bounds__(256) void prep_qkv_bias(const float* bQ, const float* bK, const float* bV,
                                                     float* __restrict__ out)
{
    int idx = blockIdx.x*256 + threadIdx.x;
    if (idx >= QKVN) return;
    int which = idx / DM, hc = idx % DM;
    const float* b = (which == 0) ? bQ : ((which == 1) ? bK : bV);
    out[idx] = b[hc];
}

// ---------------- layernorm ----------------
__device__ __forceinline__ float block_reduce_sum(float v, float* buf){
    int tid = threadIdx.x;
    buf[tid] = v; __syncthreads();
    for (int s = 128; s > 0; s >>= 1){
        if (tid < s) buf[tid] += buf[tid + s];
        __syncthreads();
    }
    float r = buf[0]; __syncthreads();
    return r;
}
__device__ __forceinline__ float block_reduce_max(float v, float* buf){
    int tid = threadIdx.x;
    buf[tid] = v; __syncthreads();
    for (int s = 128; s > 0; s >>= 1){
        if (tid < s) buf[tid] = fmaxf(buf[tid], buf[tid + s]);
        __syncthreads();
    }
    float r = buf[0]; __syncthreads();
    return r;
}

template<typename Tin>
__global__ __launch_bounds__(256) void ln_kernel(const Tin* __restrict__ x,
                                                 const float* __restrict__ w,
                                                 const float* __restrict__ b,
                                                 bf16* __restrict__ out)
{
    __shared__ float buf[256];
    int row = blockIdx.x, tid = threadIdx.x;
    const Tin* xr = x + (size_t)row*DM;
    float v[3];
    float s = 0.f, s2 = 0.f;
    #pragma unroll
    for (int i = 0; i < 3; i++){
        float t = tof(xr[tid + 256*i]);
        v[i] = t; s += t; s2 += t*t;
    }
    float sum  = block_reduce_sum(s,  buf);
    float sum2 = block_reduce_sum(s2, buf);
    float mean = sum * (1.0f/DM);
    float var  = sum2 * (1.0f/DM) - mean*mean;
    float rstd = rsqrtf(var + LN_EPS);
    #pragma unroll
    for (int i = 0; i < 3; i++){
        int c = tid + 256*i;
        out[(size_t)row*DM + c] = f2b((v[i] - mean)*rstd*w[c] + b[c]);
    }
}

// ---------------- tiled GEMM: C[M,N] = A[M,K](bf16) @ B[K,N](fp32) + bias (+gelu) (+res) ----
// EPI: 0 none, 1 gelu.  RES: 0 none, 1 bf16 residual, 2 fp32 residual.  OUT: 0 bf16, 1 fp32
template<int EPI, int RES, int OUT>
__global__ __launch_bounds__(256) void gemm_kernel(const bf16* __restrict__ A,
                                                   const float* __restrict__ B,
                                                   const float* __restrict__ bias,
                                                   const void* __restrict__ resp,
                                                   void* __restrict__ Cp,
                                                   int N, int K)
{
    __shared__ float As[16][65];   // [k][m]
    __shared__ float Bs[16][64];   // [k][n]
    int tid = threadIdx.x;
    int bx = blockIdx.x, by = blockIdx.y;
    int tx = tid & 15, ty = tid >> 4;
    int arow = tid >> 2, acol = (tid & 3)*4;
    int brow = tid >> 4, bcol = (tid & 15)*4;
    const bf16*  Ap = A + (size_t)(by*64 + arow)*K + acol;
    const float* Bp = B + (size_t)brow*N + bx*64 + bcol;
    float acc[4][4] = {};
    for (int k0 = 0; k0 < K; k0 += 16){
        ushort4 av = *(const ushort4*)(Ap + k0);
        float4  bv = *(const float4*)(Bp + (size_t)k0*N);
        __syncthreads();
        As[acol+0][arow] = us2f(av.x);
        As[acol+1][arow] = us2f(av.y);
        As[acol+2][arow] = us2f(av.z);
        As[acol+3][arow] = us2f(av.w);
        Bs[brow][bcol+0] = bv.x;
        Bs[brow][bcol+1] = bv.y;
        Bs[brow][bcol+2] = bv.z;
        Bs[brow][bcol+3] = bv.w;
        __syncthreads();
        #pragma unroll
        for (int k = 0; k < 16; k++){
            float a0 = As[k][ty*4+0], a1 = As[k][ty*4+1], a2 = As[k][ty*4+2], a3 = As[k][ty*4+3];
            float b0 = Bs[k][tx*4+0], b1 = Bs[k][tx*4+1], b2 = Bs[k][tx*4+2], b3 = Bs[k][tx*4+3];
            acc[0][0] += a0*b0; acc[0][1] += a0*b1; acc[0][2] += a0*b2; acc[0][3] += a0*b3;
            acc[1][0] += a1*b0; acc[1][1] += a1*b1; acc[1][2] += a1*b2; acc[1][3] += a1*b3;
            acc[2][0] += a2*b0; acc[2][1] += a2*b1; acc[2][2] += a2*b2; acc[2][3] += a2*b3;
            acc[3][0] += a3*b0; acc[3][1] += a3*b1; acc[3][2] += a3*b2; acc[3][3] += a3*b3;
        }
    }
    int crow0 = by*64 + ty*4;
    int ccol0 = bx*64 + tx*4;
    #pragma unroll
    for (int i = 0; i < 4; i++){
        size_t r = (size_t)(crow0 + i);
        #pragma unroll
        for (int j = 0; j < 4; j++){
            int c = ccol0 + j;
            float v = acc[i][j] + bias[c];
            if (EPI == 1) v = gelu_f(v);
            if (RES == 1) v += b2f(((const bf16*)resp)[r*N + c]);
            if (RES == 2) v += ((const float*)resp)[r*N + c];
            if (OUT == 0) ((bf16*)Cp)[r*N + c] = f2b(v);
            else          ((float*)Cp)[r*N + c] = v;
        }
    }
}

// ---------------- attention: one block per (b, h, q); qkv is bf16 ----------------
// qkv layout: row t = b*SEQ+s, 2304 cols: [0,768) Q, [768,1536) K, [1536,2304) V, col h*64+e
__global__ __launch_bounds__(256) void attn_kernel(const bf16* __restrict__ qkv,
                                                   bf16* __restrict__ z)
{
    __shared__ float qs[64];
    __shared__ float sc[SEQ];
    __shared__ float rbuf[256];
    __shared__ float part[4][64];
    int q = blockIdx.x, h = blockIdx.y, b = blockIdx.z;
    int tid = threadIdx.x;
    size_t rowq = (size_t)(b*SEQ + q);
    const bf16* qrow = qkv + rowq*QKVN + h*DH;
    if (tid < 64) qs[tid] = 0.125f * b2f(qrow[tid]);   // 1/sqrt(64) folded into Q
    __syncthreads();

    float lmax = -1e30f;
    for (int j = tid; j <= q; j += 256){
        const bf16* krow = qkv + (size_t)(b*SEQ + j)*QKVN + DM + h*DH;
        float s = 0.f;
        #pragma unroll
        for (int e = 0; e < DH; e += 2){
            __hip_bfloat162 kv = *(const __hip_bfloat162*)(krow + e);
            s += qs[e]*b2f(kv.x) + qs[e+1]*b2f(kv.y);
        }
        sc[j] = s;
        lmax = fmaxf(lmax, s);
    }
    float m = block_reduce_max(lmax, rbuf);

    float lsum = 0.f;
    for (int j = tid; j <= q; j += 256){
        float p = expf(sc[j] - m);
        sc[j] = p;
        lsum += p;
    }
    float denom = block_reduce_sum(lsum, rbuf);

    int d = tid & 63, g = tid >> 6;
    float acc = 0.f;
    for (int j = g; j <= q; j += 4){
        acc += sc[j] * b2f(qkv[(size_t)(b*SEQ + j)*QKVN + 2*DM + h*DH + d]);
    }
    part[g][d] = acc;
    __syncthreads();
    if (tid < 64){
        float t = (part[0][tid] + part[1][tid] + part[2][tid] + part[3][tid]) / denom;
        z[rowq*DM + h*DH + tid] = f2b(t);
    }
}

// ---------------- launch ----------------
// fp32 I/O; bf16 intermediates. ws arena (~60 MiB, lifetime-aliased):
//   region0 @ 0        (37,748,736 B): qkv bf16 [QKV-gemm -> attn] | hidden chunk bf16 (4096x3072) [MLP]
//   region1 @ 37748736 (12,582,912 B): ln1o -> z -> ln2o (bf16, disjoint lifetimes)
//   region2 @ 50331648 (12,582,912 B): wqkv fp32 (7.08MB) [prep -> QKV-gemm] -> resid_mid bf16 [O-gemm -> end]
//   qkvbias @ 62914560 (9,216 B) fp32
extern "C" void kernel_launch(void* const* d_in, const int* in_sizes, int n_in,
                              void* d_out, int out_size, void* d_ws, size_t ws_size,
                              hipStream_t stream)
{
    const float* resid_pre = (const float*)d_in[0];
    const float* W_Q  = (const float*)d_in[1];
    const float* W_K  = (const float*)d_in[2];
    const float* W_V  = (const float*)d_in[3];
    const float* W_O  = (const float*)d_in[4];   // [12,64,768] == [768,768] K x N
    const float* b_Q  = (const float*)d_in[5];
    const float* b_K  = (const float*)d_in[6];
    const float* b_V  = (const float*)d_in[7];
    const float* b_O  = (const float*)d_in[8];
    const float* ln1w = (const float*)d_in[9];
    const float* ln1b = (const float*)d_in[10];
    const float* ln2w = (const float*)d_in[11];
    const float* ln2b = (const float*)d_in[12];
    const float* W_in = (const float*)d_in[13];  // [768,3072] K x N
    const float* b_in = (const float*)d_in[14];
    const float* W_out= (const float*)d_in[15];  // [3072,768] K x N
    const float* b_out= (const float*)d_in[16];

    char* ws = (char*)d_ws;
    bf16*  qkv       = (bf16*) (ws);                    // region0
    bf16*  hidden    = (bf16*) (ws);                    // region0 (after qkv dead)
    bf16*  ln1o      = (bf16*) (ws + 37748736);         // region1
    bf16*  z         = (bf16*) (ws + 37748736);         // region1
    bf16*  ln2o      = (bf16*) (ws + 37748736);         // region1
    float* wqkv      = (float*)(ws + 50331648);         // region2 (early)
    bf16*  resid_mid = (bf16*) (ws + 50331648);         // region2 (late)
    float* bias_qkv  = (float*)(ws + 62914560);

    prep_wqkv<<<dim3((DM*QKVN + 255)/256), dim3(256), 0, stream>>>(W_Q, W_K, W_V, wqkv);
    prep_qkv_bias<<<dim3((QKVN + 255)/256), dim3(256), 0, stream>>>(b_Q, b_K, b_V, bias_qkv);

    // ln1 + QKV projection
    ln_kernel<float><<<dim3(NTOK), dim3(256), 0, stream>>>(resid_pre, ln1w, ln1b, ln1o);
    gemm_kernel<0,0,0><<<dim3(QKVN/64, NTOK/64), dim3(256), 0, stream>>>(
        ln1o, wqkv, bias_qkv, nullptr, qkv, QKVN, DM);

    // attention
    attn_kernel<<<dim3(SEQ, NH, BATCH), dim3(256), 0, stream>>>(qkv, z);

    // O projection + residual(fp32 resid_pre) -> resid_mid (bf16)
    gemm_kernel<0,2,0><<<dim3(DM/64, NTOK/64), dim3(256), 0, stream>>>(
        z, W_O, b_O, resid_pre, resid_mid, DM, DM);

    // ln2
    ln_kernel<bf16><<<dim3(NTOK), dim3(256), 0, stream>>>(resid_mid, ln2w, ln2b, ln2o);

    // MLP in 2 row-chunks of 4096 rows (hidden chunk fits region0)
    for (int chunk = 0; chunk < 2; chunk++){
        size_t r0 = (size_t)chunk * 4096;
        gemm_kernel<1,0,0><<<dim3(DMLP/64, 4096/64), dim3(256), 0, stream>>>(
            ln2o + r0*DM, W_in, b_in, nullptr, hidden, DMLP, DM);
        gemm_kernel<0,1,1><<<dim3(DM/64, 4096/64), dim3(256), 0, stream>>>(
            hidden, W_out, b_out, resid_mid + r0*DM, ((float*)d_out) + r0*DM, DM, DMLP);
    }
}

// Round 4
// 550.765 us; speedup vs baseline: 6.7769x; 6.7769x over previous
//
#include <hip/hip_runtime.h>
#include <hip/hip_bf16.h>
#include <math.h>

#define DM 768
#define NH 12
#define DH 64
#define DMLP 3072
#define BATCH 8
#define SEQ 1024
#define NTOK (BATCH*SEQ)
#define QKVN (3*DM)
#define LN_EPS 1e-5f

typedef __hip_bfloat16 bf16;
typedef __attribute__((ext_vector_type(8))) short bf16x8;
typedef __attribute__((ext_vector_type(4))) float f32x4;

__device__ __forceinline__ float us2f(unsigned short u){
    unsigned int i = ((unsigned int)u) << 16; float f; __builtin_memcpy(&f, &i, 4); return f;
}
__device__ __forceinline__ short f2bs(float f){
    bf16 h = __float2bfloat16(f); short s; __builtin_memcpy(&s, &h, 2); return s;
}
__device__ __forceinline__ float tof(float x){ return x; }
__device__ __forceinline__ float tof(short x){ return us2f((unsigned short)x); }

__device__ __forceinline__ float gelu_f(float x){
    float x3 = x*x*x;
    return 0.5f*x*(1.0f + tanhf(0.7978845608028654f*(x + 0.044715f*x3)));
}

// async 16B global->LDS (m97 pattern). LDS dest = wave-uniform base + lane*16.
__device__ __forceinline__ void gload16(const void* g, void* l){
    __builtin_amdgcn_global_load_lds(
        (const __attribute__((address_space(1))) void*)g,
        (__attribute__((address_space(3))) void*)l, 16, 0, 0);
}

// ---------------- transpose + fp32->bf16 convert: out[N][K] = in[K][N] ----------------
__global__ __launch_bounds__(256) void transpose_cvt(const float* __restrict__ in,
                                                     short* __restrict__ out,
                                                     int K, int N)
{
    __shared__ float t[32][33];
    int n0 = blockIdx.x*32, k0 = blockIdx.y*32;
    int tx = threadIdx.x & 31, ty = threadIdx.x >> 5;
    #pragma unroll
    for (int i = 0; i < 32; i += 8)
        t[ty+i][tx] = in[(size_t)(k0+ty+i)*N + n0+tx];
    __syncthreads();
    #pragma unroll
    for (int i = 0; i < 32; i += 8)
        out[(size_t)(n0+ty+i)*K + k0+tx] = f2bs(t[tx][ty+i]);
}

// qkv weights: W_{q,k,v}[h][k][e] -> wqkvT[n = which*768 + h*64 + e][k], bf16
// grid (2, 24, 36): z = which*12 + h; per-z: in [768][64] -> out [64][768]
__global__ __launch_bounds__(256) void transpose_cvt_qkv(const float* __restrict__ Wq,
                                                         const float* __restrict__ Wk,
                                                         const float* __restrict__ Wv,
                                                         short* __restrict__ out)
{
    __shared__ float t[32][33];
    int zz = blockIdx.z;
    int which = zz / 12, h = zz % 12;
    const float* in = (which == 0 ? Wq : which == 1 ? Wk : Wv) + (size_t)h*DM*DH;
    short* o = out + ((size_t)which*DM + h*DH)*DM;
    int n0 = blockIdx.x*32, k0 = blockIdx.y*32;
    int tx = threadIdx.x & 31, ty = threadIdx.x >> 5;
    #pragma unroll
    for (int i = 0; i < 32; i += 8)
        t[ty+i][tx] = in[(size_t)(k0+ty+i)*DH + n0+tx];
    __syncthreads();
    #pragma unroll
    for (int i = 0; i < 32; i += 8)
        o[(size_t)(n0+ty+i)*DM + k0+tx] = f2bs(t[tx][ty+i]);
}

// concat b_Q|b_K|b_V -> [2304] fp32
__global__ __launch_bounds__(256) void prep_qkv_bias(const float* bQ, const float* bK, const float* bV,
                                                     float* __restrict__ out)
{
    int idx = blockIdx.x*256 + threadIdx.x;
    if (idx >= QKVN) return;
    int which = idx / DM, hc = idx % DM;
    const float* b = (which == 0) ? bQ : ((which == 1) ? bK : bV);
    out[idx] = b[hc];
}

// ---------------- layernorm ----------------
__device__ __forceinline__ float block_reduce_sum(float v, float* buf){
    int tid = threadIdx.x;
    buf[tid] = v; __syncthreads();
    for (int s = 128; s > 0; s >>= 1){
        if (tid < s) buf[tid] += buf[tid + s];
        __syncthreads();
    }
    float r = buf[0]; __syncthreads();
    return r;
}

template<typename Tin>
__global__ __launch_bounds__(256) void ln_kernel(const Tin* __restrict__ x,
                                                 const float* __restrict__ w,
                                                 const float* __restrict__ b,
                                                 short* __restrict__ out)
{
    __shared__ float buf[256];
    int row = blockIdx.x, tid = threadIdx.x;
    const Tin* xr = x + (size_t)row*DM;
    float v[3];
    float s = 0.f, s2 = 0.f;
    #pragma unroll
    for (int i = 0; i < 3; i++){
        float t = tof(xr[tid + 256*i]);
        v[i] = t; s += t; s2 += t*t;
    }
    float sum  = block_reduce_sum(s,  buf);
    float sum2 = block_reduce_sum(s2, buf);
    float mean = sum * (1.0f/DM);
    float var  = sum2 * (1.0f/DM) - mean*mean;
    float rstd = rsqrtf(var + LN_EPS);
    #pragma unroll
    for (int i = 0; i < 3; i++){
        int c = tid + 256*i;
        out[(size_t)row*DM + c] = f2bs((v[i] - mean)*rstd*w[c] + b[c]);
    }
}

// ---------------- MFMA B^T GEMM: C[M,N] = A[M,K] @ Bt[N,K]^T ----------------
// A, Bt: bf16 (raw shorts). 128x128 tile, BK=32, 4 waves, 4x4 16x16x32 frags/wave.
// EPI: 0 none, 1 gelu. RES: 0 none, 1 bf16, 2 fp32. OUT: 0 bf16, 1 fp32.
template<int EPI, int RES, int OUT>
__global__ __launch_bounds__(256) void gemm_bt(const short* __restrict__ A,
                                               const short* __restrict__ Bt,
                                               const float* __restrict__ bias,
                                               const void* __restrict__ resp,
                                               void* __restrict__ Cp,
                                               int N, int K)
{
    __shared__ alignas(16) short As[128*32];
    __shared__ alignas(16) short Bs[128*32];
    int tid = threadIdx.x;
    int lane = tid & 63, w = tid >> 6;
    int l15 = lane & 15, quad = lane >> 4;
    int m_base = blockIdx.y*128, n_base = blockIdx.x*128;

    // staging: wave w owns 1KB chunks {2w, 2w+1} of both tiles.
    // chunk c covers tile rows 16c..16c+15 (row = 32 bf16 = 64B); lane l -> row 16c + l/4, seg (l&3)*8
    int ca = 2*w, r4 = lane >> 2, s8 = (lane & 3)*8;
    const short* gA0 = A  + (size_t)(m_base + ca*16 + r4)*K + s8;
    const short* gA1 = gA0 + (size_t)16*K;
    const short* gB0 = Bt + (size_t)(n_base + ca*16 + r4)*K + s8;
    const short* gB1 = gB0 + (size_t)16*K;
    short* lA0 = As + ca*512; short* lA1 = lA0 + 512;
    short* lB0 = Bs + ca*512; short* lB1 = lB0 + 512;

    int mrow0 = (w >> 1)*64, ncol0 = (w & 1)*64;
    f32x4 acc[4][4] = {};

    for (int k0 = 0; k0 < K; k0 += 32){
        __syncthreads();
        gload16(gA0 + k0, lA0);
        gload16(gA1 + k0, lA1);
        gload16(gB0 + k0, lB0);
        gload16(gB1 + k0, lB1);
        __syncthreads();   // vmcnt drained by compiler before barrier
        bf16x8 af[4], bfr[4];
        #pragma unroll
        for (int i = 0; i < 4; i++)
            af[i] = *(const bf16x8*)(As + (mrow0 + 16*i + l15)*32 + quad*8);
        #pragma unroll
        for (int j = 0; j < 4; j++)
            bfr[j] = *(const bf16x8*)(Bs + (ncol0 + 16*j + l15)*32 + quad*8);
        #pragma unroll
        for (int i = 0; i < 4; i++)
            #pragma unroll
            for (int j = 0; j < 4; j++)
                acc[i][j] = __builtin_amdgcn_mfma_f32_16x16x32_bf16(af[i], bfr[j], acc[i][j], 0, 0, 0);
    }

    // epilogue: C row = quad*4+reg (+16i), col = l15 (+16j)
    #pragma unroll
    for (int i = 0; i < 4; i++){
        #pragma unroll
        for (int j = 0; j < 4; j++){
            #pragma unroll
            for (int r = 0; r < 4; r++){
                size_t row = (size_t)(m_base + mrow0 + 16*i + quad*4 + r);
                int    col = n_base + ncol0 + 16*j + l15;
                float v = acc[i][j][r] + bias[col];
                if (EPI == 1) v = gelu_f(v);
                if (RES == 1) v += us2f(((const unsigned short*)resp)[row*N + col]);
                if (RES == 2) v += ((const float*)resp)[row*N + col];
                if (OUT == 0) ((short*)Cp)[row*N + col] = f2bs(v);
                else          ((float*)Cp)[row*N + col] = v;
            }
        }
    }
}

// ---------------- MFMA flash attention ----------------
// qkv [8192][2304] bf16: cols [0,768) Q, [768,1536) K, [1536,2304) V; col h*64+e.
// block = (qt, h, b), 256 thr = 4 waves; wave w owns q rows qt*64 + w*16 .. +15.
__global__ __launch_bounds__(256) void flash_attn(const short* __restrict__ qkv,
                                                  short* __restrict__ z)
{
    __shared__ alignas(16) short Qs[64][72];
    __shared__ alignas(16) short Ks[64][72];
    __shared__ alignas(16) short Vt[64][72];    // Vt[d][key]
    __shared__ alignas(16) short Ps[4][16][72]; // per-wave P
    int qt = blockIdx.x, h = blockIdx.y, b = blockIdx.z;
    int tid = threadIdx.x, lane = tid & 63, w = tid >> 6;
    int l15 = lane & 15, quad = lane >> 4;

    // stage Q tile (rows qt*64..+63, cols h*64..+63)
    {
        int r = tid >> 2, seg = (tid & 3)*16;
        const short* src = qkv + (size_t)(b*SEQ + qt*64 + r)*QKVN + h*DH + seg;
        bf16x8 v0 = *(const bf16x8*)(src);
        bf16x8 v1 = *(const bf16x8*)(src + 8);
        *(bf16x8*)&Qs[r][seg]     = v0;
        *(bf16x8*)&Qs[r][seg + 8] = v1;
    }
    __syncthreads();

    bf16x8 aq[2];
    aq[0] = *(const bf16x8*)&Qs[w*16 + l15][quad*8];
    aq[1] = *(const bf16x8*)&Qs[w*16 + l15][32 + quad*8];

    float m_state[4] = {-1e30f, -1e30f, -1e30f, -1e30f};
    float l_state[4] = {0.f, 0.f, 0.f, 0.f};
    f32x4 o_acc[4] = {};
    int rg = qt*64 + w*16 + quad*4;   // global q row for reg 0

    for (int kt = 0; kt <= qt; ++kt){
        __syncthreads();   // protect Ks/Vt from previous iteration's readers
        {
            int r = tid >> 2, seg = (tid & 3)*16;
            const short* ksrc = qkv + (size_t)(b*SEQ + kt*64 + r)*QKVN + DM + h*DH + seg;
            bf16x8 k0 = *(const bf16x8*)(ksrc);
            bf16x8 k1 = *(const bf16x8*)(ksrc + 8);
            *(bf16x8*)&Ks[r][seg]     = k0;
            *(bf16x8*)&Ks[r][seg + 8] = k1;
            const short* vsrc = qkv + (size_t)(b*SEQ + kt*64 + r)*QKVN + 2*DM + h*DH + seg;
            bf16x8 v0 = *(const bf16x8*)(vsrc);
            bf16x8 v1 = *(const bf16x8*)(vsrc + 8);
            #pragma unroll
            for (int i = 0; i < 8; i++) Vt[seg + i][r]     = v0[i];
            #pragma unroll
            for (int i = 0; i < 8; i++) Vt[seg + 8 + i][r] = v1[i];
        }
        __syncthreads();

        // S = Q K^T (16 q x 64 key per wave)
        f32x4 s[4] = {};
        #pragma unroll
        for (int j = 0; j < 4; j++){
            bf16x8 bk0 = *(const bf16x8*)&Ks[16*j + l15][quad*8];
            bf16x8 bk1 = *(const bf16x8*)&Ks[16*j + l15][32 + quad*8];
            s[j] = __builtin_amdgcn_mfma_f32_16x16x32_bf16(aq[0], bk0, s[j], 0, 0, 0);
            s[j] = __builtin_amdgcn_mfma_f32_16x16x32_bf16(aq[1], bk1, s[j], 0, 0, 0);
        }

        // scale + causal mask (diagonal tile only)
        bool diag = (kt == qt);
        #pragma unroll
        for (int j = 0; j < 4; j++){
            int col_g = kt*64 + 16*j + l15;
            #pragma unroll
            for (int r = 0; r < 4; r++){
                float v = s[j][r] * 0.125f;
                if (diag && col_g > rg + r) v = -1e30f;
                s[j][r] = v;
            }
        }

        // online softmax per row (rows = quad*4 + r; reduce across the 16 lanes of the quad-group)
        #pragma unroll
        for (int r = 0; r < 4; r++){
            float mx = fmaxf(fmaxf(s[0][r], s[1][r]), fmaxf(s[2][r], s[3][r]));
            #pragma unroll
            for (int d = 1; d < 16; d <<= 1) mx = fmaxf(mx, __shfl_xor(mx, d, 64));
            float m_new = fmaxf(m_state[r], mx);
            float alpha = __expf(m_state[r] - m_new);
            m_state[r] = m_new;
            float rs = 0.f;
            #pragma unroll
            for (int j = 0; j < 4; j++){
                float p = __expf(s[j][r] - m_new);
                s[j][r] = p; rs += p;
            }
            #pragma unroll
            for (int d = 1; d < 16; d <<= 1) rs += __shfl_xor(rs, d, 64);
            l_state[r] = l_state[r]*alpha + rs;
            #pragma unroll
            for (int j = 0; j < 4; j++) o_acc[j][r] *= alpha;
        }

        // P -> LDS (bf16, per-wave region; wave-internal ordering via lgkmcnt)
        #pragma unroll
        for (int j = 0; j < 4; j++)
            #pragma unroll
            for (int r = 0; r < 4; r++)
                Ps[w][quad*4 + r][16*j + l15] = f2bs(s[j][r]);

        // O += P V  (A = P rows key-contig, B = Vt rows key-contig)
        #pragma unroll
        for (int kk = 0; kk < 2; kk++){
            bf16x8 ap = *(const bf16x8*)&Ps[w][l15][32*kk + quad*8];
            #pragma unroll
            for (int j = 0; j < 4; j++){
                bf16x8 bv = *(const bf16x8*)&Vt[16*j + l15][32*kk + quad*8];
                o_acc[j] = __builtin_amdgcn_mfma_f32_16x16x32_bf16(ap, bv, o_acc[j], 0, 0, 0);
            }
        }
    }

    // epilogue: z[row][h*64 + col] = o / l
    #pragma unroll
    for (int r = 0; r < 4; r++){
        float inv_l = 1.0f / l_state[r];
        size_t row = (size_t)(b*SEQ + rg + r);
        #pragma unroll
        for (int j = 0; j < 4; j++)
            z[row*DM + h*DH + 16*j + l15] = f2bs(o_acc[j][r] * inv_l);
    }
}

// ---------------- launch ----------------
// ws map (59,778,048 B total):
//   [0        , 3538944 ) wqkvT bf16 [prep -> qkv-gemm]   } overlaid later by
//   [3538944  , 4718592 ) WOT  bf16 [prep -> O-gemm]      } WinT bf16 (4,718,592) [post-O-gemm -> MLP]
//   [4718592  , 4727808 ) bias_qkv fp32 [prep -> qkv-gemm]
//   [4727808  ,42476544 ) R1: qkv bf16 (37.75MB) [qkv-gemm -> attn];
//                         then resid_mid bf16 @+0 (12.58MB) [O-gemm -> end],
//                         hidden bf16 @+12582912 (25.17MB, 4096-row chunks) [MLP]
//   [42476544 ,55059456 ) R2: ln1o -> z -> ln2o (bf16)
//   [55059456 ,59778048 ) WoutT bf16 [prep -> MLP]
extern "C" void kernel_launch(void* const* d_in, const int* in_sizes, int n_in,
                              void* d_out, int out_size, void* d_ws, size_t ws_size,
                              hipStream_t stream)
{
    const float* resid_pre = (const float*)d_in[0];
    const float* W_Q  = (const float*)d_in[1];
    const float* W_K  = (const float*)d_in[2];
    const float* W_V  = (const float*)d_in[3];
    const float* W_O  = (const float*)d_in[4];   // [768][768] K x N
    const float* b_Q  = (const float*)d_in[5];
    const float* b_K  = (const float*)d_in[6];
    const float* b_V  = (const float*)d_in[7];
    const float* b_O  = (const float*)d_in[8];
    const float* ln1w = (const float*)d_in[9];
    const float* ln1b = (const float*)d_in[10];
    const float* ln2w = (const float*)d_in[11];
    const float* ln2b = (const float*)d_in[12];
    const float* W_in = (const float*)d_in[13];  // [768][3072] K x N
    const float* b_in = (const float*)d_in[14];
    const float* W_out= (const float*)d_in[15];  // [3072][768] K x N
    const float* b_out= (const float*)d_in[16];

    char* ws = (char*)d_ws;
    short* wqkvT     = (short*)(ws);
    short* WOT       = (short*)(ws + 3538944);
    float* bias_qkv  = (float*)(ws + 4718592);
    short* WinT      = (short*)(ws);             // overlays wqkvT+WOT after O-gemm
    short* qkv       = (short*)(ws + 4727808);   // R1
    short* resid_mid = (short*)(ws + 4727808);   // R1 (post-attn)
    short* hidden    = (short*)(ws + 4727808 + 12582912);
    short* ln1o      = (short*)(ws + 42476544);  // R2
    short* zbuf      = (short*)(ws + 42476544);
    short* ln2o      = (short*)(ws + 42476544);
    short* WoutT     = (short*)(ws + 55059456);

    // prep: weight transposes + bias concat
    transpose_cvt_qkv<<<dim3(2, 24, 36), dim3(256), 0, stream>>>(W_Q, W_K, W_V, wqkvT);
    prep_qkv_bias<<<dim3(9), dim3(256), 0, stream>>>(b_Q, b_K, b_V, bias_qkv);
    transpose_cvt<<<dim3(24, 24), dim3(256), 0, stream>>>(W_O,   WOT,   DM,   DM);
    transpose_cvt<<<dim3(24, 96), dim3(256), 0, stream>>>(W_out, WoutT, DMLP, DM);

    // ln1 + QKV projection
    ln_kernel<float><<<dim3(NTOK), dim3(256), 0, stream>>>(resid_pre, ln1w, ln1b, ln1o);
    gemm_bt<0,0,0><<<dim3(QKVN/128, NTOK/128), dim3(256), 0, stream>>>(
        ln1o, wqkvT, bias_qkv, nullptr, qkv, QKVN, DM);

    // attention
    flash_attn<<<dim3(SEQ/64, NH, BATCH), dim3(256), 0, stream>>>(qkv, zbuf);

    // O projection + residual(fp32) -> resid_mid bf16 (qkv dead)
    gemm_bt<0,2,0><<<dim3(DM/128, NTOK/128), dim3(256), 0, stream>>>(
        zbuf, WOT, b_O, resid_pre, resid_mid, DM, DM);

    // W_in transpose (wqkvT/WOT dead now)
    transpose_cvt<<<dim3(96, 24), dim3(256), 0, stream>>>(W_in, WinT, DM, DMLP);

    // ln2
    ln_kernel<short><<<dim3(NTOK), dim3(256), 0, stream>>>(resid_mid, ln2w, ln2b, ln2o);

    // MLP in 2 chunks of 4096 rows
    for (int chunk = 0; chunk < 2; chunk++){
        size_t r0 = (size_t)chunk * 4096;
        gemm_bt<1,0,0><<<dim3(DMLP/128, 4096/128), dim3(256), 0, stream>>>(
            ln2o + r0*DM, WinT, b_in, nullptr, hidden, DMLP, DM);
        gemm_bt<0,1,1><<<dim3(DM/128, 4096/128), dim3(256), 0, stream>>>(
            hidden, WoutT, b_out, resid_mid + r0*DM, (float*)d_out + r0*DM, DM, DMLP);
    }
}

// Round 5
// 444.108 us; speedup vs baseline: 8.4045x; 1.2402x over previous
//
#include <hip/hip_runtime.h>
#include <hip/hip_bf16.h>
#include <math.h>

#define DM 768
#define NH 12
#define DH 64
#define DMLP 3072
#define BATCH 8
#define SEQ 1024
#define NTOK (BATCH*SEQ)
#define QKVN (3*DM)
#define LN_EPS 1e-5f

typedef __hip_bfloat16 bf16;
typedef __attribute__((ext_vector_type(8))) short bf16x8;
typedef __attribute__((ext_vector_type(4))) float f32x4;

#define MFMA16(a,b,c) __builtin_amdgcn_mfma_f32_16x16x32_bf16((a),(b),(c),0,0,0)

__device__ __forceinline__ float us2f(unsigned short u){
    unsigned int i = ((unsigned int)u) << 16; float f; __builtin_memcpy(&f, &i, 4); return f;
}
__device__ __forceinline__ short f2bs(float f){
    bf16 h = __float2bfloat16(f); short s; __builtin_memcpy(&s, &h, 2); return s;
}

__device__ __forceinline__ float gelu_f(float x){
    float x3 = x*x*x;
    return 0.5f*x*(1.0f + tanhf(0.7978845608028654f*(x + 0.044715f*x3)));
}

// async 16B global->LDS. LDS dest = wave-uniform base + lane*16 (fixed linear).
__device__ __forceinline__ void gload16(const void* g, void* l){
    __builtin_amdgcn_global_load_lds(
        (const __attribute__((address_space(1))) void*)g,
        (__attribute__((address_space(3))) void*)l, 16, 0, 0);
}

// ---------------- transpose + fp32->bf16 convert: out[N][K] = in[K][N] ----------------
__global__ __launch_bounds__(256) void transpose_cvt(const float* __restrict__ in,
                                                     short* __restrict__ out,
                                                     int K, int N)
{
    __shared__ float t[32][33];
    int n0 = blockIdx.x*32, k0 = blockIdx.y*32;
    int tx = threadIdx.x & 31, ty = threadIdx.x >> 5;
    #pragma unroll
    for (int i = 0; i < 32; i += 8)
        t[ty+i][tx] = in[(size_t)(k0+ty+i)*N + n0+tx];
    __syncthreads();
    #pragma unroll
    for (int i = 0; i < 32; i += 8)
        out[(size_t)(n0+ty+i)*K + k0+tx] = f2bs(t[tx][ty+i]);
}

// qkv weights: W_{q,k,v}[h][k][e] -> wqkvT[n = which*768 + h*64 + e][k], bf16
__global__ __launch_bounds__(256) void transpose_cvt_qkv(const float* __restrict__ Wq,
                                                         const float* __restrict__ Wk,
                                                         const float* __restrict__ Wv,
                                                         short* __restrict__ out)
{
    __shared__ float t[32][33];
    int zz = blockIdx.z;
    int which = zz / 12, h = zz % 12;
    const float* in = (which == 0 ? Wq : which == 1 ? Wk : Wv) + (size_t)h*DM*DH;
    short* o = out + ((size_t)which*DM + h*DH)*DM;
    int n0 = blockIdx.x*32, k0 = blockIdx.y*32;
    int tx = threadIdx.x & 31, ty = threadIdx.x >> 5;
    #pragma unroll
    for (int i = 0; i < 32; i += 8)
        t[ty+i][tx] = in[(size_t)(k0+ty+i)*DH + n0+tx];
    __syncthreads();
    #pragma unroll
    for (int i = 0; i < 32; i += 8)
        o[(size_t)(n0+ty+i)*DM + k0+tx] = f2bs(t[tx][ty+i]);
}

// concat b_Q|b_K|b_V -> [2304] fp32
__global__ __launch_bounds__(256) void prep_qkv_bias(const float* bQ, const float* bK, const float* bV,
                                                     float* __restrict__ out)
{
    int idx = blockIdx.x*256 + threadIdx.x;
    if (idx >= QKVN) return;
    int which = idx / DM, hc = idx % DM;
    const float* b = (which == 0) ? bQ : ((which == 1) ? bK : bV);
    out[idx] = b[hc];
}

// v_rm [8192][768] bf16 -> vT [(b*12+h)*64 + d][1024] bf16
__global__ __launch_bounds__(256) void transpose_v(const short* __restrict__ v_rm,
                                                   short* __restrict__ vT)
{
    __shared__ short t[64][65];
    int st = blockIdx.x, h = blockIdx.y, b = blockIdx.z;
    int tok = threadIdx.x >> 2, seg = (threadIdx.x & 3)*16;
    const short* src = v_rm + (size_t)(b*SEQ + st*64 + tok)*DM + h*DH + seg;
    bf16x8 a0 = *(const bf16x8*)src;
    bf16x8 a1 = *(const bf16x8*)(src + 8);
    #pragma unroll
    for (int i = 0; i < 8; i++) t[seg + i][tok]     = a0[i];
    #pragma unroll
    for (int i = 0; i < 8; i++) t[seg + 8 + i][tok] = a1[i];
    __syncthreads();
    int d = threadIdx.x >> 2; int sk = (threadIdx.x & 3)*16;
    short* dst = vT + ((size_t)(b*NH + h)*DH + d)*SEQ + st*64 + sk;
    bf16x8 w0, w1;
    #pragma unroll
    for (int i = 0; i < 8; i++) w0[i] = t[d][sk + i];
    #pragma unroll
    for (int i = 0; i < 8; i++) w1[i] = t[d][sk + 8 + i];
    *(bf16x8*)dst = w0;
    *(bf16x8*)(dst + 8) = w1;
}

// ---------------- layernorm (fp32 in, bf16 out) ----------------
__device__ __forceinline__ float block_reduce_sum(float v, float* buf){
    int tid = threadIdx.x;
    buf[tid] = v; __syncthreads();
    for (int s = 128; s > 0; s >>= 1){
        if (tid < s) buf[tid] += buf[tid + s];
        __syncthreads();
    }
    float r = buf[0]; __syncthreads();
    return r;
}

__global__ __launch_bounds__(256) void ln_kernel(const float* __restrict__ x,
                                                 const float* __restrict__ w,
                                                 const float* __restrict__ b,
                                                 short* __restrict__ out)
{
    __shared__ float buf[256];
    int row = blockIdx.x, tid = threadIdx.x;
    const float* xr = x + (size_t)row*DM;
    float v[3];
    float s = 0.f, s2 = 0.f;
    #pragma unroll
    for (int i = 0; i < 3; i++){
        float t = xr[tid + 256*i];
        v[i] = t; s += t; s2 += t*t;
    }
    float sum  = block_reduce_sum(s,  buf);
    float sum2 = block_reduce_sum(s2, buf);
    float mean = sum * (1.0f/DM);
    float var  = sum2 * (1.0f/DM) - mean*mean;
    float rstd = rsqrtf(var + LN_EPS);
    #pragma unroll
    for (int i = 0; i < 3; i++){
        int c = tid + 256*i;
        out[(size_t)row*DM + c] = f2bs((v[i] - mean)*rstd*w[c] + b[c]);
    }
}

// ---------------- MFMA B^T GEMM, 128x128 tile, BK=64, XOR-swizzled LDS ----------------
// C[M,N] = A[M,K] @ Bt[N,K]^T. EPI: 1=gelu. RES: 2=fp32 residual. OUT: 0 bf16, 1 fp32.
// SPLITV: cols<1536 -> Cp (stride 1536), cols>=1536 -> Cp2 (stride 768), both bf16.
template<int EPI, int RES, int OUT, int SPLITV>
__global__ __launch_bounds__(256) void gemm_bt(const short* __restrict__ A,
                                               const short* __restrict__ Bt,
                                               const float* __restrict__ bias,
                                               const void* __restrict__ resp,
                                               void* __restrict__ Cp,
                                               void* __restrict__ Cp2,
                                               int N, int K)
{
    __shared__ alignas(16) short As[128*64];
    __shared__ alignas(16) short Bs[128*64];
    int tid = threadIdx.x, lane = tid & 63, w = tid >> 6;
    int l15 = lane & 15, quad = lane >> 4;
    int m_base = blockIdx.y*128, n_base = blockIdx.x*128;

    // staging: chunk = 8 rows x 64 shorts (1KB); wave w stages A/B chunks 4w..4w+3.
    int r8 = lane >> 3, u = lane & 7;
    int useg = (u ^ r8) * 8;                         // swizzled k-seg (shorts)
    const short* gA = A  + (size_t)(m_base + 32*w + r8)*K + useg;
    const short* gB = Bt + (size_t)(n_base + 32*w + r8)*K + useg;

    int mrow0 = (w >> 1)*64, ncol0 = (w & 1)*64;
    f32x4 acc[4][4] = {};

    for (int k0 = 0; k0 < K; k0 += 64){
        __syncthreads();
        #pragma unroll
        for (int c = 0; c < 4; c++){
            gload16(gA + (size_t)(8*c)*K + k0, As + (4*w + c)*512);
            gload16(gB + (size_t)(8*c)*K + k0, Bs + (4*w + c)*512);
        }
        __syncthreads();
        #pragma unroll
        for (int kk = 0; kk < 2; kk++){
            bf16x8 af[4], bfr[4];
            int swz = ((4*kk + quad) ^ (l15 & 7)) * 8;
            #pragma unroll
            for (int i = 0; i < 4; i++)
                af[i] = *(const bf16x8*)(As + (mrow0 + 16*i + l15)*64 + swz);
            #pragma unroll
            for (int j = 0; j < 4; j++)
                bfr[j] = *(const bf16x8*)(Bs + (ncol0 + 16*j + l15)*64 + swz);
            #pragma unroll
            for (int i = 0; i < 4; i++)
                #pragma unroll
                for (int j = 0; j < 4; j++)
                    acc[i][j] = MFMA16(af[i], bfr[j], acc[i][j]);
        }
    }

    #pragma unroll
    for (int i = 0; i < 4; i++){
        #pragma unroll
        for (int j = 0; j < 4; j++){
            #pragma unroll
            for (int r = 0; r < 4; r++){
                size_t row = (size_t)(m_base + mrow0 + 16*i + quad*4 + r);
                int    col = n_base + ncol0 + 16*j + l15;
                float v = acc[i][j][r] + bias[col];
                if (EPI == 1) v = gelu_f(v);
                if (RES == 2) v += ((const float*)resp)[row*N + col];
                if (SPLITV){
                    if (col < 1536) ((short*)Cp )[row*1536 + col]        = f2bs(v);
                    else            ((short*)Cp2)[row*768  + col - 1536] = f2bs(v);
                } else if (OUT == 0) ((short*)Cp)[row*N + col] = f2bs(v);
                else                 ((float*)Cp)[row*N + col] = v;
            }
        }
    }
}

// ---------------- thin MFMA GEMM: 128x64 tile, BK=64, swizzled ----------------
template<int EPI, int RES, int OUT>
__global__ __launch_bounds__(256) void gemm_bt_thin(const short* __restrict__ A,
                                                    const short* __restrict__ Bt,
                                                    const float* __restrict__ bias,
                                                    const void* __restrict__ resp,
                                                    void* __restrict__ Cp,
                                                    int N, int K)
{
    __shared__ alignas(16) short As[128*64];
    __shared__ alignas(16) short Bs[64*64];
    int tid = threadIdx.x, lane = tid & 63, w = tid >> 6;
    int l15 = lane & 15, quad = lane >> 4;
    int m_base = blockIdx.y*128, n_base = blockIdx.x*64;

    int r8 = lane >> 3, u = lane & 7;
    int useg = (u ^ r8) * 8;
    const short* gA = A  + (size_t)(m_base + 32*w + r8)*K + useg;
    const short* gB = Bt + (size_t)(n_base + 16*w + r8)*K + useg;

    f32x4 acc[2][4] = {};

    for (int k0 = 0; k0 < K; k0 += 64){
        __syncthreads();
        #pragma unroll
        for (int c = 0; c < 4; c++)
            gload16(gA + (size_t)(8*c)*K + k0, As + (4*w + c)*512);
        #pragma unroll
        for (int c = 0; c < 2; c++)
            gload16(gB + (size_t)(8*c)*K + k0, Bs + (2*w + c)*512);
        __syncthreads();
        #pragma unroll
        for (int kk = 0; kk < 2; kk++){
            bf16x8 af[2], bfr[4];
            int swz = ((4*kk + quad) ^ (l15 & 7)) * 8;
            #pragma unroll
            for (int i = 0; i < 2; i++)
                af[i] = *(const bf16x8*)(As + (32*w + 16*i + l15)*64 + swz);
            #pragma unroll
            for (int j = 0; j < 4; j++)
                bfr[j] = *(const bf16x8*)(Bs + (16*j + l15)*64 + swz);
            #pragma unroll
            for (int i = 0; i < 2; i++)
                #pragma unroll
                for (int j = 0; j < 4; j++)
                    acc[i][j] = MFMA16(af[i], bfr[j], acc[i][j]);
        }
    }

    #pragma unroll
    for (int i = 0; i < 2; i++){
        #pragma unroll
        for (int j = 0; j < 4; j++){
            #pragma unroll
            for (int r = 0; r < 4; r++){
                size_t row = (size_t)(m_base + 32*w + 16*i + quad*4 + r);
                int    col = n_base + 16*j + l15;
                float v = acc[i][j][r] + bias[col];
                if (EPI == 1) v = gelu_f(v);
                if (RES == 2) v += ((const float*)resp)[row*N + col];
                if (OUT == 0) ((short*)Cp)[row*N + col] = f2bs(v);
                else          ((float*)Cp)[row*N + col] = v;
            }
        }
    }
}

// ---------------- MFMA flash attention v2 ----------------
// qk [8192][1536]: cols [0,768) Q, [768,1536) K (col h*64+e). vT [(b*12+h)*64+d][1024].
// block = (pair p, h, b): processes q-tiles p and 15-p (17 kt-iters, balanced).
__global__ __launch_bounds__(256) void flash_attn(const short* __restrict__ qk,
                                                  const short* __restrict__ vT,
                                                  short* __restrict__ z)
{
    __shared__ alignas(16) short U[4608];     // 9216B: Q tile [64][64] (swz) / Ps [4][16][72]
    __shared__ alignas(16) short Ks[64*64];   // swizzled
    __shared__ alignas(16) short Vt[64*64];   // swizzled, rows = d
    int p = blockIdx.x, h = blockIdx.y, b = blockIdx.z;
    int tid = threadIdx.x, lane = tid & 63, w = tid >> 6;
    int l15 = lane & 15, quad = lane >> 4;
    int r8 = lane >> 3, u = lane & 7;
    int useg = (u ^ r8) * 8;

    for (int phase = 0; phase < 2; phase++){
        int qt = phase ? (15 - p) : p;

        __syncthreads();   // prior phase's Ks/Vt/U readers done
        #pragma unroll
        for (int c = 0; c < 2; c++){
            const short* g = qk + (size_t)(b*SEQ + qt*64 + 16*w + 8*c + r8)*1536 + h*DH + useg;
            gload16(g, U + (2*w + c)*512);
        }
        __syncthreads();   // drain staging

        bf16x8 aq[2];
        #pragma unroll
        for (int kk = 0; kk < 2; kk++)
            aq[kk] = *(const bf16x8*)(U + (16*w + l15)*64 + (((4*kk + quad) ^ (l15 & 7))*8));

        float m_state[4] = {-1e30f,-1e30f,-1e30f,-1e30f};
        float l_state[4] = {0.f,0.f,0.f,0.f};
        f32x4 o_acc[4] = {};
        int rg = qt*64 + w*16 + quad*4;

        for (int kt = 0; kt <= qt; ++kt){
            __syncthreads();   // protect Ks/Vt from previous iteration's readers
            #pragma unroll
            for (int c = 0; c < 2; c++){
                const short* gk = qk + (size_t)(b*SEQ + kt*64 + 16*w + 8*c + r8)*1536 + DM + h*DH + useg;
                gload16(gk, Ks + (2*w + c)*512);
                const short* gv = vT + ((size_t)(b*NH + h)*DH + 16*w + 8*c + r8)*SEQ + kt*64 + useg;
                gload16(gv, Vt + (2*w + c)*512);
            }
            __syncthreads();

            // S = Q K^T (16 q x 64 key per wave)
            f32x4 s[4] = {};
            #pragma unroll
            for (int kk = 0; kk < 2; kk++){
                int swz = ((4*kk + quad) ^ (l15 & 7)) * 8;
                #pragma unroll
                for (int j = 0; j < 4; j++){
                    bf16x8 bk = *(const bf16x8*)(Ks + (16*j + l15)*64 + swz);
                    s[j] = MFMA16(aq[kk], bk, s[j]);
                }
            }

            // scale + causal mask (diagonal tile only)
            bool diag = (kt == qt);
            #pragma unroll
            for (int j = 0; j < 4; j++){
                int col_g = kt*64 + 16*j + l15;
                #pragma unroll
                for (int r = 0; r < 4; r++){
                    float v = s[j][r] * 0.125f;
                    if (diag && col_g > rg + r) v = -1e30f;
                    s[j][r] = v;
                }
            }

            // online softmax (rows = quad*4 + r; reduce across 16 lanes of quad-group)
            #pragma unroll
            for (int r = 0; r < 4; r++){
                float mx = fmaxf(fmaxf(s[0][r], s[1][r]), fmaxf(s[2][r], s[3][r]));
                #pragma unroll
                for (int d = 1; d < 16; d <<= 1) mx = fmaxf(mx, __shfl_xor(mx, d, 64));
                float m_new = fmaxf(m_state[r], mx);
                float alpha = __expf(m_state[r] - m_new);
                m_state[r] = m_new;
                float rs = 0.f;
                #pragma unroll
                for (int j = 0; j < 4; j++){
                    float pv = __expf(s[j][r] - m_new);
                    s[j][r] = pv; rs += pv;
                }
                #pragma unroll
                for (int d = 1; d < 16; d <<= 1) rs += __shfl_xor(rs, d, 64);
                l_state[r] = l_state[r]*alpha + rs;
                #pragma unroll
                for (int j = 0; j < 4; j++) o_acc[j][r] *= alpha;
            }

            // P -> LDS (bf16, wave-private region of U; stride 72)
            #pragma unroll
            for (int j = 0; j < 4; j++)
                #pragma unroll
                for (int r = 0; r < 4; r++)
                    U[w*1152 + (quad*4 + r)*72 + 16*j + l15] = f2bs(s[j][r]);

            // O += P V
            #pragma unroll
            for (int kk = 0; kk < 2; kk++){
                bf16x8 ap = *(const bf16x8*)(U + w*1152 + l15*72 + 32*kk + quad*8);
                int swz = ((4*kk + quad) ^ (l15 & 7)) * 8;
                #pragma unroll
                for (int j = 0; j < 4; j++){
                    bf16x8 bv = *(const bf16x8*)(Vt + (16*j + l15)*64 + swz);
                    o_acc[j] = MFMA16(ap, bv, o_acc[j]);
                }
            }
        }

        // epilogue: z[row][h*64 + col] = o / l
        #pragma unroll
        for (int r = 0; r < 4; r++){
            float inv_l = 1.0f / l_state[r];
            size_t row = (size_t)(b*SEQ + rg + r);
            #pragma unroll
            for (int j = 0; j < 4; j++)
                z[row*DM + h*DH + 16*j + l15] = f2bs(o_acc[j][r] * inv_l);
        }
    }
}

// ---------------- launch ----------------
// ws map (59,778,048 B, lifetime-aliased):
//   A0 [0, 3538944)          wqkvT               -> WinT (A0+A1) after O-gemm
//   A1 [3538944, 4718592)    WOT
//   A2 [4718592, 4727808)    bias_qkv fp32
//   A3 [4727808, 29893632)   qk bf16 [qkv-gemm -> flash] -> hidden chunk (25.17MB) [MLP]
//   A4 [29893632, 42476544)  v_rm [qkv-gemm -> transpose_v] -> zbuf [flash -> O-gemm]
//   A5 [42476544, 55059456)  ln1o [ln1 -> qkv-gemm] -> vT [transpose_v -> flash] -> ln2o [MLP]
//   A6 [55059456, 59778048)  WoutT
// resid_mid lives in d_out (fp32): O-gemm writes it, ln2 reads it, final gemm adds+overwrites.
extern "C" void kernel_launch(void* const* d_in, const int* in_sizes, int n_in,
                              void* d_out, int out_size, void* d_ws, size_t ws_size,
                              hipStream_t stream)
{
    const float* resid_pre = (const float*)d_in[0];
    const float* W_Q  = (const float*)d_in[1];
    const float* W_K  = (const float*)d_in[2];
    const float* W_V  = (const float*)d_in[3];
    const float* W_O  = (const float*)d_in[4];
    const float* b_Q  = (const float*)d_in[5];
    const float* b_K  = (const float*)d_in[6];
    const float* b_V  = (const float*)d_in[7];
    const float* b_O  = (const float*)d_in[8];
    const float* ln1w = (const float*)d_in[9];
    const float* ln1b = (const float*)d_in[10];
    const float* ln2w = (const float*)d_in[11];
    const float* ln2b = (const float*)d_in[12];
    const float* W_in = (const float*)d_in[13];
    const float* b_in = (const float*)d_in[14];
    const float* W_out= (const float*)d_in[15];
    const float* b_out= (const float*)d_in[16];

    char* ws = (char*)d_ws;
    short* wqkvT    = (short*)(ws);
    short* WOT      = (short*)(ws + 3538944);
    float* bias_qkv = (float*)(ws + 4718592);
    short* WinT     = (short*)(ws);             // after O-gemm
    short* qk       = (short*)(ws + 4727808);   // A3
    short* hidden   = (short*)(ws + 4727808);   // A3 after flash
    short* v_rm     = (short*)(ws + 29893632);  // A4
    short* zbuf     = (short*)(ws + 29893632);  // A4 after transpose_v
    short* ln1o     = (short*)(ws + 42476544);  // A5
    short* vT       = (short*)(ws + 42476544);  // A5 after qkv-gemm
    short* ln2o     = (short*)(ws + 42476544);  // A5 after flash
    short* WoutT    = (short*)(ws + 55059456);  // A6

    // prep
    transpose_cvt_qkv<<<dim3(2, 24, 36), dim3(256), 0, stream>>>(W_Q, W_K, W_V, wqkvT);
    prep_qkv_bias<<<dim3(9), dim3(256), 0, stream>>>(b_Q, b_K, b_V, bias_qkv);
    transpose_cvt<<<dim3(24, 24), dim3(256), 0, stream>>>(W_O,   WOT,   DM,   DM);
    transpose_cvt<<<dim3(24, 96), dim3(256), 0, stream>>>(W_out, WoutT, DMLP, DM);

    // ln1 + QKV projection (split: Q,K -> qk[.][1536], V -> v_rm[.][768])
    ln_kernel<<<dim3(NTOK), dim3(256), 0, stream>>>(resid_pre, ln1w, ln1b, ln1o);
    gemm_bt<0,0,0,1><<<dim3(QKVN/128, NTOK/128), dim3(256), 0, stream>>>(
        ln1o, wqkvT, bias_qkv, nullptr, qk, v_rm, QKVN, DM);

    // V transpose then flash attention
    transpose_v<<<dim3(SEQ/64, NH, BATCH), dim3(256), 0, stream>>>(v_rm, vT);
    flash_attn<<<dim3(SEQ/128, NH, BATCH), dim3(256), 0, stream>>>(qk, vT, zbuf);

    // O projection + residual(resid_pre fp32) -> d_out fp32
    gemm_bt_thin<0,2,1><<<dim3(DM/64, NTOK/128), dim3(256), 0, stream>>>(
        zbuf, WOT, b_O, resid_pre, d_out, DM, DM);

    // W_in transpose (A0/A1 dead)
    transpose_cvt<<<dim3(96, 24), dim3(256), 0, stream>>>(W_in, WinT, DM, DMLP);

    // ln2 on d_out (fp32)
    ln_kernel<<<dim3(NTOK), dim3(256), 0, stream>>>((const float*)d_out, ln2w, ln2b, ln2o);

    // MLP in 2 chunks of 4096 rows; final gemm reads+writes d_out in place
    for (int chunk = 0; chunk < 2; chunk++){
        size_t r0 = (size_t)chunk * 4096;
        gemm_bt<1,0,0,0><<<dim3(DMLP/128, 4096/128), dim3(256), 0, stream>>>(
            ln2o + r0*DM, WinT, b_in, nullptr, hidden, nullptr, DMLP, DM);
        gemm_bt_thin<0,2,1><<<dim3(DM/64, 4096/128), dim3(256), 0, stream>>>(
            hidden, WoutT, b_out, (float*)d_out + r0*DM, (float*)d_out + r0*DM, DM, DMLP);
    }
}